// Round 6
// baseline (21.640 us; speedup 1.0000x reference)
//
#include <hip/hip_runtime.h>

#define PROTON_F 1.00782503207f
#define WATER_F 18.0105646863f
#define HUBER_DELTA_F 0.2f

constexpr int B = 512;
constexpr int L = 64;
constexpr int V = 28;
constexpr int M = 1024;
constexpr int THREADS = 256;
constexpr int PROW = 29;          // padded LDS row stride (29 coprime 32)

// Fused single-kernel version. Last-block-done detection uses a mod-512
// window on an uninitialized counter: atomicAdd over 512 blocks sweeps 512
// consecutive integers, so exactly one block sees prev % 512 == 511 for ANY
// initial counter value (poison, garbage, or leftover from prior replays).
// => no memset node, no dependence on buffer state, identical work each call.

__global__ __launch_bounds__(THREADS)
void spectrum_loss_fused(const float* __restrict__ probs,       // [B, L, V]
                         const float* __restrict__ obs_mass,    // [B, M]
                         const float* __restrict__ obs_int,     // [B, M]
                         const int* __restrict__ mask,          // [B, M] (bool->int32)
                         const float* __restrict__ aa,          // [V]
                         float* __restrict__ per_b,             // [B] scratch
                         unsigned* __restrict__ counter,        // [1] scratch (uninit ok)
                         float* __restrict__ out)               // [1]
{
    const int b = blockIdx.x;
    const int tid = threadIdx.x;
    const int lane = tid & 63;
    const int wave = tid >> 6;

    __shared__ float s_probs[L * PROW];  // 7.25 KiB
    __shared__ float s_bA[64];           // ascending b_ions + inf sentinel
    __shared__ float s_yA[64];           // ascending (reversed) y_ions + inf
    __shared__ float s_red[8];
    __shared__ int s_last;

    // ---- issue observed-peak loads FIRST: HBM latency hides under probs phase
    const size_t obase = (size_t)b * M;
    const float4 om4 = ((const float4*)(obs_mass + obase))[tid];
    const float4 oi4 = ((const float4*)(obs_int + obase))[tid];
    const int4   mk4 = ((const int4*)(mask + obase))[tid];

    // ---- stage probs[b] into LDS (float4, padded rows)
    const float4* p4 = (const float4*)(probs + (size_t)b * (L * V));
    #pragma unroll
    for (int j = tid; j < (L * V) / 4; j += THREADS) {   // 448 float4s
        const float4 v = p4[j];
        float* dst = &s_probs[(j / 7) * PROW + (j % 7) * 4];
        dst[0] = v.x; dst[1] = v.y; dst[2] = v.z; dst[3] = v.w;
    }
    __syncthreads();

    // ---- wave 0: dot, Kogge-Stone shuffle cumsum, build sorted peak arrays
    if (wave == 0) {
        float r = 0.f;
        #pragma unroll
        for (int c = 0; c < 7; ++c) {
            const float4 a = ((const float4*)aa)[c];
            const float* pr = &s_probs[lane * PROW + c * 4];
            r += pr[0] * a.x + pr[1] * a.y + pr[2] * a.z + pr[3] * a.w;
        }
        float pref = r;
        #pragma unroll
        for (int off = 1; off < 64; off <<= 1) {
            const float t = __shfl_up(pref, off, 64);
            if (lane >= off) pref += t;
        }
        const float total = __shfl(pref, 63, 64);
        s_bA[lane] = (lane < 63) ? pref + PROTON_F : 1e30f;
        if (lane < 63) s_yA[62 - lane] = total - pref + WATER_F + PROTON_F;
        else           s_yA[63] = 1e30f;
    }
    __syncthreads();

    // ---- branchless lower-bound binary search, 4 obs peaks x 2 arrays
    const float omv0 = om4.x, omv1 = om4.y, omv2 = om4.z, omv3 = om4.w;
    int ib0 = 0, ib1 = 0, ib2 = 0, ib3 = 0;
    int iy0 = 0, iy1 = 0, iy2 = 0, iy3 = 0;
    #pragma unroll
    for (int k = 32; k >= 1; k >>= 1) {
        ib0 += (s_bA[ib0 + k - 1] < omv0) ? k : 0;
        ib1 += (s_bA[ib1 + k - 1] < omv1) ? k : 0;
        ib2 += (s_bA[ib2 + k - 1] < omv2) ? k : 0;
        ib3 += (s_bA[ib3 + k - 1] < omv3) ? k : 0;
        iy0 += (s_yA[iy0 + k - 1] < omv0) ? k : 0;
        iy1 += (s_yA[iy1 + k - 1] < omv1) ? k : 0;
        iy2 += (s_yA[iy2 + k - 1] < omv2) ? k : 0;
        iy3 += (s_yA[iy3 + k - 1] < omv3) ? k : 0;
    }
    float mind0, mind1, mind2, mind3;
    {
        float db, dy;
        db = fminf(fabsf(s_bA[ib0] - omv0), fabsf(s_bA[ib0 - (ib0 > 0)] - omv0));
        dy = fminf(fabsf(s_yA[iy0] - omv0), fabsf(s_yA[iy0 - (iy0 > 0)] - omv0));
        mind0 = fminf(db, dy);
        db = fminf(fabsf(s_bA[ib1] - omv1), fabsf(s_bA[ib1 - (ib1 > 0)] - omv1));
        dy = fminf(fabsf(s_yA[iy1] - omv1), fabsf(s_yA[iy1 - (iy1 > 0)] - omv1));
        mind1 = fminf(db, dy);
        db = fminf(fabsf(s_bA[ib2] - omv2), fabsf(s_bA[ib2 - (ib2 > 0)] - omv2));
        dy = fminf(fabsf(s_yA[iy2] - omv2), fabsf(s_yA[iy2 - (iy2 > 0)] - omv2));
        mind2 = fminf(db, dy);
        db = fminf(fabsf(s_bA[ib3] - omv3), fabsf(s_bA[ib3 - (ib3 > 0)] - omv3));
        dy = fminf(fabsf(s_yA[iy3] - omv3), fabsf(s_yA[iy3 - (iy3 > 0)] - omv3));
        mind3 = fminf(db, dy);
    }

    // ---- huber, weight, per-thread partial sums
    float wsum = 0.f, isum = 0.f;
    {
        float d, h;
        d = mind0; h = (d <= HUBER_DELTA_F) ? 0.5f * d * d
                                            : HUBER_DELTA_F * (d - 0.5f * HUBER_DELTA_F);
        wsum += h * oi4.x * (float)mk4.x;  isum += oi4.x;
        d = mind1; h = (d <= HUBER_DELTA_F) ? 0.5f * d * d
                                            : HUBER_DELTA_F * (d - 0.5f * HUBER_DELTA_F);
        wsum += h * oi4.y * (float)mk4.y;  isum += oi4.y;
        d = mind2; h = (d <= HUBER_DELTA_F) ? 0.5f * d * d
                                            : HUBER_DELTA_F * (d - 0.5f * HUBER_DELTA_F);
        wsum += h * oi4.z * (float)mk4.z;  isum += oi4.z;
        d = mind3; h = (d <= HUBER_DELTA_F) ? 0.5f * d * d
                                            : HUBER_DELTA_F * (d - 0.5f * HUBER_DELTA_F);
        wsum += h * oi4.w * (float)mk4.w;  isum += oi4.w;
    }

    // ---- wave shuffle reduction, then 4 wave-sums via LDS
    #pragma unroll
    for (int off = 32; off > 0; off >>= 1) {
        wsum += __shfl_down(wsum, off, 64);
        isum += __shfl_down(isum, off, 64);
    }
    if (lane == 0) { s_red[wave] = wsum; s_red[4 + wave] = isum; }
    __syncthreads();

    // ---- publish per_b, detect last block via mod-512 window (init-free)
    if (tid == 0) {
        const float w = s_red[0] + s_red[1] + s_red[2] + s_red[3];
        const float i = s_red[4] + s_red[5] + s_red[6] + s_red[7];
        const float pb = w / fmaxf(i, 1e-8f);
        __hip_atomic_store(&per_b[b], pb, __ATOMIC_RELEASE, __HIP_MEMORY_SCOPE_AGENT);
        const unsigned prev = __hip_atomic_fetch_add(counter, 1u,
                                                     __ATOMIC_ACQ_REL,
                                                     __HIP_MEMORY_SCOPE_AGENT);
        s_last = ((prev & (unsigned)(B - 1)) == (unsigned)(B - 1));
    }
    __syncthreads();

    // ---- exactly one block (the 512th to finish) reduces per_b -> mean
    if (s_last) {
        const float v0 = __hip_atomic_load(&per_b[tid], __ATOMIC_ACQUIRE,
                                           __HIP_MEMORY_SCOPE_AGENT);
        const float v1 = __hip_atomic_load(&per_b[tid + THREADS], __ATOMIC_ACQUIRE,
                                           __HIP_MEMORY_SCOPE_AGENT);
        float v = v0 + v1;
        #pragma unroll
        for (int off = 32; off > 0; off >>= 1)
            v += __shfl_down(v, off, 64);
        if (lane == 0) s_red[wave] = v;
        __syncthreads();
        if (tid == 0)
            out[0] = (s_red[0] + s_red[1] + s_red[2] + s_red[3]) * (1.0f / (float)B);
    }
}

extern "C" void kernel_launch(void* const* d_in, const int* in_sizes, int n_in,
                              void* d_out, int out_size, void* d_ws, size_t ws_size,
                              hipStream_t stream)
{
    const float* probs = (const float*)d_in[0];
    const float* omass = (const float*)d_in[1];
    const float* oint  = (const float*)d_in[2];
    const int*   pmask = (const int*)d_in[3];
    const float* aa    = (const float*)d_in[4];
    float* out  = (float*)d_out;

    float*    perb    = (float*)d_ws;                    // 512 floats, rewritten each call
    unsigned* counter = (unsigned*)((char*)d_ws + 4096); // separate line; NO init needed

    spectrum_loss_fused<<<B, THREADS, 0, stream>>>(probs, omass, oint, pmask, aa,
                                                   perb, counter, out);
}

// Round 7
// 17.707 us; speedup vs baseline: 1.2221x; 1.2221x over previous
//
#include <hip/hip_runtime.h>

#define PROTON_F 1.00782503207f
#define WATER_F 18.0105646863f
#define HUBER_DELTA_F 0.2f

constexpr int B = 512;
constexpr int L = 64;
constexpr int V = 28;
constexpr int M = 1024;
constexpr int THREADS = 256;

// Single fused kernel.
// - Last-block detection: atomicAdd on an UNINITIALIZED counter; 512 adds sweep
//   512 consecutive integers, so exactly one block sees prev % 512 == 511 for
//   any initial value (poison/garbage/leftover). No memset node, stateless.
// - Coherence: producers publish per_b with a relaxed agent-scope store
//   (write-through to coherence point) + one __threadfence(); the tail does one
//   __threadfence() then relaxed agent-scope loads. ONE fence per block and two
//   in the tail -- no per-load acquire cache-invalidates (Round-6 mistake).

__global__ __launch_bounds__(THREADS)
void spectrum_loss_fused(const float* __restrict__ probs,       // [B, L, V]
                         const float* __restrict__ obs_mass,    // [B, M]
                         const float* __restrict__ obs_int,     // [B, M]
                         const int* __restrict__ mask,          // [B, M] (bool->int32)
                         const float* __restrict__ aa,          // [V]
                         float* __restrict__ per_b,             // [B] scratch
                         unsigned* __restrict__ counter,        // [1] scratch (uninit ok)
                         float* __restrict__ out)               // [1]
{
    const int b = blockIdx.x;
    const int tid = threadIdx.x;
    const int lane = tid & 63;
    const int wave = tid >> 6;

    __shared__ float s_bA[64];           // ascending b_ions + inf sentinel
    __shared__ float s_yA[64];           // ascending (reversed) y_ions + inf
    __shared__ float s_red[8];
    __shared__ int s_last;

    // ---- issue observed-peak loads FIRST: HBM latency hides under dot phase
    const size_t obase = (size_t)b * M;
    const float4 om4 = ((const float4*)(obs_mass + obase))[tid];
    const float4 oi4 = ((const float4*)(obs_int + obase))[tid];
    const int4   mk4 = ((const int4*)(mask + obase))[tid];

    // ---- wave 0: dot from global, Kogge-Stone cumsum, sorted peak arrays
    if (wave == 0) {
        const float* prow = probs + (size_t)b * (L * V) + lane * V;  // 112B-aligned
        float r = 0.f;
        #pragma unroll
        for (int c = 0; c < 7; ++c) {
            const float4 p = ((const float4*)prow)[c];
            const float4 a = ((const float4*)aa)[c];
            r += p.x * a.x + p.y * a.y + p.z * a.z + p.w * a.w;
        }
        float pref = r;
        #pragma unroll
        for (int off = 1; off < 64; off <<= 1) {
            const float t = __shfl_up(pref, off, 64);
            if (lane >= off) pref += t;
        }
        const float total = __shfl(pref, 63, 64);
        s_bA[lane] = (lane < 63) ? pref + PROTON_F : 1e30f;
        if (lane < 63) s_yA[62 - lane] = total - pref + WATER_F + PROTON_F;
        else           s_yA[63] = 1e30f;
    }
    __syncthreads();

    // ---- branchless lower-bound binary search, 4 obs peaks x 2 arrays
    const float omv0 = om4.x, omv1 = om4.y, omv2 = om4.z, omv3 = om4.w;
    int ib0 = 0, ib1 = 0, ib2 = 0, ib3 = 0;
    int iy0 = 0, iy1 = 0, iy2 = 0, iy3 = 0;
    #pragma unroll
    for (int k = 32; k >= 1; k >>= 1) {
        ib0 += (s_bA[ib0 + k - 1] < omv0) ? k : 0;
        ib1 += (s_bA[ib1 + k - 1] < omv1) ? k : 0;
        ib2 += (s_bA[ib2 + k - 1] < omv2) ? k : 0;
        ib3 += (s_bA[ib3 + k - 1] < omv3) ? k : 0;
        iy0 += (s_yA[iy0 + k - 1] < omv0) ? k : 0;
        iy1 += (s_yA[iy1 + k - 1] < omv1) ? k : 0;
        iy2 += (s_yA[iy2 + k - 1] < omv2) ? k : 0;
        iy3 += (s_yA[iy3 + k - 1] < omv3) ? k : 0;
    }
    float mind0, mind1, mind2, mind3;
    {
        float db, dy;
        db = fminf(fabsf(s_bA[ib0] - omv0), fabsf(s_bA[ib0 - (ib0 > 0)] - omv0));
        dy = fminf(fabsf(s_yA[iy0] - omv0), fabsf(s_yA[iy0 - (iy0 > 0)] - omv0));
        mind0 = fminf(db, dy);
        db = fminf(fabsf(s_bA[ib1] - omv1), fabsf(s_bA[ib1 - (ib1 > 0)] - omv1));
        dy = fminf(fabsf(s_yA[iy1] - omv1), fabsf(s_yA[iy1 - (iy1 > 0)] - omv1));
        mind1 = fminf(db, dy);
        db = fminf(fabsf(s_bA[ib2] - omv2), fabsf(s_bA[ib2 - (ib2 > 0)] - omv2));
        dy = fminf(fabsf(s_yA[iy2] - omv2), fabsf(s_yA[iy2 - (iy2 > 0)] - omv2));
        mind2 = fminf(db, dy);
        db = fminf(fabsf(s_bA[ib3] - omv3), fabsf(s_bA[ib3 - (ib3 > 0)] - omv3));
        dy = fminf(fabsf(s_yA[iy3] - omv3), fabsf(s_yA[iy3 - (iy3 > 0)] - omv3));
        mind3 = fminf(db, dy);
    }

    // ---- huber, weight, per-thread partial sums
    float wsum = 0.f, isum = 0.f;
    {
        float d, h;
        d = mind0; h = (d <= HUBER_DELTA_F) ? 0.5f * d * d
                                            : HUBER_DELTA_F * (d - 0.5f * HUBER_DELTA_F);
        wsum += h * oi4.x * (float)mk4.x;  isum += oi4.x;
        d = mind1; h = (d <= HUBER_DELTA_F) ? 0.5f * d * d
                                            : HUBER_DELTA_F * (d - 0.5f * HUBER_DELTA_F);
        wsum += h * oi4.y * (float)mk4.y;  isum += oi4.y;
        d = mind2; h = (d <= HUBER_DELTA_F) ? 0.5f * d * d
                                            : HUBER_DELTA_F * (d - 0.5f * HUBER_DELTA_F);
        wsum += h * oi4.z * (float)mk4.z;  isum += oi4.z;
        d = mind3; h = (d <= HUBER_DELTA_F) ? 0.5f * d * d
                                            : HUBER_DELTA_F * (d - 0.5f * HUBER_DELTA_F);
        wsum += h * oi4.w * (float)mk4.w;  isum += oi4.w;
    }

    // ---- wave shuffle reduction, then 4 wave-sums via LDS
    #pragma unroll
    for (int off = 32; off > 0; off >>= 1) {
        wsum += __shfl_down(wsum, off, 64);
        isum += __shfl_down(isum, off, 64);
    }
    if (lane == 0) { s_red[wave] = wsum; s_red[4 + wave] = isum; }
    __syncthreads();

    // ---- publish per_b, detect last block via mod-512 window (init-free)
    if (tid == 0) {
        const float w = s_red[0] + s_red[1] + s_red[2] + s_red[3];
        const float i = s_red[4] + s_red[5] + s_red[6] + s_red[7];
        const float pb = w / fmaxf(i, 1e-8f);
        // relaxed agent-scope store: write-through to coherence point, no
        // whole-cache release op
        __hip_atomic_store(&per_b[b], pb, __ATOMIC_RELAXED, __HIP_MEMORY_SCOPE_AGENT);
        __threadfence();   // order the store before the counter add
        const unsigned prev = atomicAdd(counter, 1u);  // device-scope default
        s_last = ((prev & (unsigned)(B - 1)) == (unsigned)(B - 1));
    }
    __syncthreads();

    // ---- exactly one block (the 512th to finish) reduces per_b -> mean
    if (s_last) {
        __threadfence();   // one consumer-side fence, NOT per-load acquires
        const float v0 = __hip_atomic_load(&per_b[tid], __ATOMIC_RELAXED,
                                           __HIP_MEMORY_SCOPE_AGENT);
        const float v1 = __hip_atomic_load(&per_b[tid + THREADS], __ATOMIC_RELAXED,
                                           __HIP_MEMORY_SCOPE_AGENT);
        float v = v0 + v1;
        #pragma unroll
        for (int off = 32; off > 0; off >>= 1)
            v += __shfl_down(v, off, 64);
        if (lane == 0) s_red[wave] = v;
        __syncthreads();
        if (tid == 0)
            out[0] = (s_red[0] + s_red[1] + s_red[2] + s_red[3]) * (1.0f / (float)B);
    }
}

extern "C" void kernel_launch(void* const* d_in, const int* in_sizes, int n_in,
                              void* d_out, int out_size, void* d_ws, size_t ws_size,
                              hipStream_t stream)
{
    const float* probs = (const float*)d_in[0];
    const float* omass = (const float*)d_in[1];
    const float* oint  = (const float*)d_in[2];
    const int*   pmask = (const int*)d_in[3];
    const float* aa    = (const float*)d_in[4];
    float* out  = (float*)d_out;

    float*    perb    = (float*)d_ws;                    // 512 floats, rewritten each call
    unsigned* counter = (unsigned*)((char*)d_ws + 4096); // separate line; NO init needed

    spectrum_loss_fused<<<B, THREADS, 0, stream>>>(probs, omass, oint, pmask, aa,
                                                   perb, counter, out);
}

// Round 8
// 10.911 us; speedup vs baseline: 1.9834x; 1.6229x over previous
//
#include <hip/hip_runtime.h>

#define PROTON_F 1.00782503207f
#define WATER_F 18.0105646863f
#define HUBER_DELTA_F 0.2f

constexpr int B = 512;
constexpr int L = 64;
constexpr int V = 28;
constexpr int M = 1024;
constexpr int THREADS = 512;      // 8 waves/block, 2 blocks/CU -> 16 waves/CU

// Two-kernel structure (fused single-kernel proven slower in R6/R7: per-block
// cross-XCD publication costs more than a second dispatch).
// Kernel1: one block per batch row b. Theoretical peaks are two SORTED arrays
// (b_ions ascend, y_ions stored reversed); min|T-m| via 6-step branchless
// lower-bound binary search. 2 observed peaks per thread.

__global__ __launch_bounds__(THREADS)
void spectrum_loss_main(const float* __restrict__ probs,       // [B, L, V]
                        const float* __restrict__ obs_mass,    // [B, M]
                        const float* __restrict__ obs_int,     // [B, M]
                        const int* __restrict__ mask,          // [B, M] (bool->int32)
                        const float* __restrict__ aa,          // [V]
                        float* __restrict__ per_b)             // [B]
{
    const int b = blockIdx.x;
    const int tid = threadIdx.x;
    const int lane = tid & 63;
    const int wave = tid >> 6;

    __shared__ float s_bA[64];           // ascending b_ions + inf sentinel
    __shared__ float s_yA[64];           // ascending (reversed) y_ions + inf
    __shared__ float s_red[16];

    // ---- issue observed-peak loads FIRST: HBM latency hides under dot phase
    const size_t obase = (size_t)b * M;
    const float2 om2 = ((const float2*)(obs_mass + obase))[tid];
    const float2 oi2 = ((const float2*)(obs_int + obase))[tid];
    const int2   mk2 = ((const int2*)(mask + obase))[tid];

    // ---- wave 0: dot from global, Kogge-Stone cumsum, sorted peak arrays
    if (wave == 0) {
        const float* prow = probs + (size_t)b * (L * V) + lane * V;  // 112B-aligned
        float r = 0.f;
        #pragma unroll
        for (int c = 0; c < 7; ++c) {
            const float4 p = ((const float4*)prow)[c];
            const float4 a = ((const float4*)aa)[c];
            r += p.x * a.x + p.y * a.y + p.z * a.z + p.w * a.w;
        }
        float pref = r;
        #pragma unroll
        for (int off = 1; off < 64; off <<= 1) {
            const float t = __shfl_up(pref, off, 64);
            if (lane >= off) pref += t;
        }
        const float total = __shfl(pref, 63, 64);
        s_bA[lane] = (lane < 63) ? pref + PROTON_F : 1e30f;
        if (lane < 63) s_yA[62 - lane] = total - pref + WATER_F + PROTON_F;
        else           s_yA[63] = 1e30f;
    }
    __syncthreads();

    // ---- branchless lower-bound binary search, 2 obs peaks x 2 arrays
    const float omv0 = om2.x, omv1 = om2.y;
    int ib0 = 0, ib1 = 0, iy0 = 0, iy1 = 0;
    #pragma unroll
    for (int k = 32; k >= 1; k >>= 1) {
        ib0 += (s_bA[ib0 + k - 1] < omv0) ? k : 0;
        ib1 += (s_bA[ib1 + k - 1] < omv1) ? k : 0;
        iy0 += (s_yA[iy0 + k - 1] < omv0) ? k : 0;
        iy1 += (s_yA[iy1 + k - 1] < omv1) ? k : 0;
    }
    float mind0, mind1;
    {
        float db, dy;
        db = fminf(fabsf(s_bA[ib0] - omv0), fabsf(s_bA[ib0 - (ib0 > 0)] - omv0));
        dy = fminf(fabsf(s_yA[iy0] - omv0), fabsf(s_yA[iy0 - (iy0 > 0)] - omv0));
        mind0 = fminf(db, dy);
        db = fminf(fabsf(s_bA[ib1] - omv1), fabsf(s_bA[ib1 - (ib1 > 0)] - omv1));
        dy = fminf(fabsf(s_yA[iy1] - omv1), fabsf(s_yA[iy1 - (iy1 > 0)] - omv1));
        mind1 = fminf(db, dy);
    }

    // ---- huber, weight, per-thread partial sums
    float wsum = 0.f, isum = 0.f;
    {
        float d, h;
        d = mind0; h = (d <= HUBER_DELTA_F) ? 0.5f * d * d
                                            : HUBER_DELTA_F * (d - 0.5f * HUBER_DELTA_F);
        wsum += h * oi2.x * (float)mk2.x;  isum += oi2.x;
        d = mind1; h = (d <= HUBER_DELTA_F) ? 0.5f * d * d
                                            : HUBER_DELTA_F * (d - 0.5f * HUBER_DELTA_F);
        wsum += h * oi2.y * (float)mk2.y;  isum += oi2.y;
    }

    // ---- wave shuffle reduction, then 8 wave-sums via LDS (single barrier)
    #pragma unroll
    for (int off = 32; off > 0; off >>= 1) {
        wsum += __shfl_down(wsum, off, 64);
        isum += __shfl_down(isum, off, 64);
    }
    if (lane == 0) { s_red[wave] = wsum; s_red[8 + wave] = isum; }
    __syncthreads();

    if (tid == 0) {
        const float w = (s_red[0] + s_red[1]) + (s_red[2] + s_red[3])
                      + (s_red[4] + s_red[5]) + (s_red[6] + s_red[7]);
        const float i = (s_red[8] + s_red[9]) + (s_red[10] + s_red[11])
                      + (s_red[12] + s_red[13]) + (s_red[14] + s_red[15]);
        per_b[b] = w / fmaxf(i, 1e-8f);
    }
}

// Single wave: 64 threads x 8 values, pure shuffle reduce, no LDS, no barriers.
__global__ __launch_bounds__(64)
void final_reduce_wave(const float* __restrict__ per_b, float* __restrict__ out)
{
    const int lane = threadIdx.x;
    const float4 a = ((const float4*)per_b)[lane * 2];
    const float4 c = ((const float4*)per_b)[lane * 2 + 1];
    float v = (a.x + a.y) + (a.z + a.w) + (c.x + c.y) + (c.z + c.w);
    #pragma unroll
    for (int off = 32; off > 0; off >>= 1)
        v += __shfl_down(v, off, 64);
    if (lane == 0) out[0] = v * (1.0f / (float)B);
}

extern "C" void kernel_launch(void* const* d_in, const int* in_sizes, int n_in,
                              void* d_out, int out_size, void* d_ws, size_t ws_size,
                              hipStream_t stream)
{
    const float* probs = (const float*)d_in[0];
    const float* omass = (const float*)d_in[1];
    const float* oint  = (const float*)d_in[2];
    const int*   pmask = (const int*)d_in[3];
    const float* aa    = (const float*)d_in[4];
    float* out  = (float*)d_out;
    float* perb = (float*)d_ws;  // 512 floats, fully rewritten each call

    spectrum_loss_main<<<B, THREADS, 0, stream>>>(probs, omass, oint, pmask, aa, perb);
    final_reduce_wave<<<1, 64, 0, stream>>>(perb, out);
}